// Round 8
// baseline (287.939 us; speedup 1.0000x reference)
//
#include <hip/hip_runtime.h>
#include <cstdint>

#define DEV __device__ __forceinline__

typedef float f32x4 __attribute__((ext_vector_type(4)));
typedef short s16x8 __attribute__((ext_vector_type(8)));

DEV unsigned short f2bf(float f){
    unsigned u = __builtin_bit_cast(unsigned, f);
    u = u + 0x7fffu + ((u >> 16) & 1u);   // RNE
    return (unsigned short)(u >> 16);
}
DEV float bf2f(unsigned short h){
    unsigned u = ((unsigned)h) << 16;
    return __builtin_bit_cast(float, u);
}

typedef const void __attribute__((address_space(1)))* gcp;
typedef void __attribute__((address_space(3)))* lp;
DEV void gload_lds16(const void* g, void* l){
    // async global->LDS, 16B per lane; LDS dest = wave-uniform base + lane*16
    __builtin_amdgcn_global_load_lds((gcp)g, (lp)l, 16, 0, 0);
}

#define LDSFENCE asm volatile("s_waitcnt lgkmcnt(0)" ::: "memory")
#define GFENCE   asm volatile("s_waitcnt vmcnt(0)"  ::: "memory")

// ---------------------------------------------------------------------------
// Stage 1 (grid 6145), static LDS 17.8 KB -> 8 blocks/CU (thread-capped):
//   block 0          : dragon pattern (single wave; A in LDS, scratch Bb in
//                      GLOBAL ws so its 16 KB doesn't bloat every block's LDS;
//                      single block => same-CU L2, vmcnt(0) orders W->R) + blend
//   blocks 1..2048   : Q -> bf16
//   blocks 2049..4096: K -> bf16 (UNSCALED; dragon_w applied in qk epilogue)
//   blocks 4097..    : V -> Vt (bf16 [b][d][s]) + race-free vmean partials
// ---------------------------------------------------------------------------
__global__ __launch_bounds__(256) void k_stage1(
    const float* __restrict__ Q, const float* __restrict__ K,
    const float* __restrict__ V,
    const float* __restrict__ scale, const float* __restrict__ bias,
    const float* __restrict__ w1, const float* __restrict__ b1,
    const float* __restrict__ w2, const float* __restrict__ b2,
    float* __restrict__ dragon_w, float* __restrict__ blend_out,
    float* __restrict__ dscratch,
    unsigned short* __restrict__ Qb, unsigned short* __restrict__ Kb,
    unsigned short* __restrict__ Vt, float* __restrict__ vmean_part)
{
    __shared__ float sh[4544];   // 18176 B: V-tile [64][67] + 256-red; dragon A
    int tid = threadIdx.x;
    int bx  = blockIdx.x;

    if (bx == 0){
        // ---- dragon pattern: ONE wave; A in LDS, Bb in global scratch ----
        float* A  = sh;          // 4096 floats (LDS)
        float* Bb = dscratch;    // 4096 floats (global, L2-resident)
        if (tid < 64){
            if (tid == 0) A[0] = 0.5f;
            LDSFENCE;
            int len = 1;
            const float third = 1.0f/3.0f;
            for (int it = 1; it < 12; ++it){
                int n = len, nl = 2*n + 1;
                for (int i = tid; i < nl; i += 64){
                    float v;
                    if (i < n)       v = A[i];
                    else if (i == n) v = 0.5f;
                    else             v = 1.0f - A[2*n - i];
                    Bb[i] = v;
                }
                GFENCE;                      // Bb global writes -> visible to reads
                float mn = 3.4e38f, mx = -3.4e38f;
                for (int i = tid; i < nl; i += 64){
                    float s = Bb[i]*third;
                    if (i > 0)    s += Bb[i-1]*third;
                    if (i < nl-1) s += Bb[i+1]*third;
                    A[i] = s;
                    mn = fminf(mn, s); mx = fmaxf(mx, s);
                }
                #pragma unroll
                for (int off = 32; off > 0; off >>= 1){
                    mn = fminf(mn, __shfl_xor(mn, off, 64));
                    mx = fmaxf(mx, __shfl_xor(mx, off, 64));
                }
                float lo = mn, den = mx - lo + 1e-8f;
                LDSFENCE;                    // A writes done before re-read
                for (int i = tid; i < nl; i += 64) A[i] = (A[i] - lo) / den;
                LDSFENCE;
                len = nl;
            }
        }
        __syncthreads();
        // pattern[11] has length 4095 -> np.interp picks element 2i
        float sc = scale[11], bi = bias[11];
        for (int i = tid; i < 2048; i += 256){
            float x = A[2*i]*sc + bi;
            dragon_w[i] = fmaxf(x, 0.f) + log1pf(__expf(-fabsf(x)));  // softplus
        }
        if (tid < 64){
            float h = fmaxf(w1[11*64 + tid] + b1[tid], 0.f);
            float c = h * w2[tid];
            for (int off = 32; off > 0; off >>= 1) c += __shfl_xor(c, off, 64);
            if (tid == 0) blend_out[0] = 1.f/(1.f + __expf(-(c + b2[0])));
        }
        return;
    }

    if (bx <= 4096){
        // ---- Q (1..2048) / K (2049..4096) -> bf16, no scaling ----
        const float* src = (bx <= 2048) ? Q : K;
        unsigned short* dst = (bx <= 2048) ? Qb : Kb;
        int bi = (bx <= 2048) ? (bx-1) : (bx-2049);
        const long long total4 = (long long)8*2048*512/4;   // 2097152
        long long stride = 2048LL*256;
        for (long long i = (long long)bi*256 + tid; i < total4; i += stride){
            long long base = i*4;
            const float4 q = *(const float4*)(src + base);
            ushort4 qo;
            qo.x = f2bf(q.x); qo.y = f2bf(q.y); qo.z = f2bf(q.z); qo.w = f2bf(q.w);
            *(ushort4*)(dst + base) = qo;
        }
        return;
    }

    // ---- V transpose + vmean partials ----
    int t = bx - 4097;                    // 0..2047 = 32 stile x 8 dtile x 8 b
    int stile = t & 31, dtile = (t >> 5) & 7, b = t >> 8;
    int s0 = stile*64, d0 = dtile*64;
    float (*tile)[67] = (float(*)[67])sh;  // 64x67 floats = 4288
    float* red = sh + 4288;                // 256 floats
    int c4 = tid & 15, rr = tid >> 4;
    const float* src = V + ((long long)b*2048 + s0)*512 + d0;
    #pragma unroll
    for (int p = 0; p < 4; ++p){
        int row = p*16 + rr;
        const float4 v = *(const float4*)(src + (long long)row*512 + c4*4);
        tile[row][c4*4+0] = v.x; tile[row][c4*4+1] = v.y;
        tile[row][c4*4+2] = v.z; tile[row][c4*4+3] = v.w;
    }
    __syncthreads();
    unsigned short* dst = Vt + ((long long)b*512 + d0)*2048 + s0;
    #pragma unroll
    for (int p = 0; p < 4; ++p){
        int d = p*16 + rr;
        ushort4 o;
        o.x = f2bf(tile[c4*4+0][d]);
        o.y = f2bf(tile[c4*4+1][d]);
        o.z = f2bf(tile[c4*4+2][d]);
        o.w = f2bf(tile[c4*4+3][d]);
        *(ushort4*)(dst + (long long)d*2048 + c4*4) = o;
    }
    int dcol = tid & 63, sp = tid >> 6;
    float s = 0.f;
    #pragma unroll
    for (int ii = 0; ii < 16; ++ii) s += tile[sp*16 + ii][dcol];
    red[sp*64 + dcol] = s;
    __syncthreads();
    if (sp == 0){
        float tot = red[dcol] + red[64+dcol] + red[128+dcol] + red[192+dcol];
        vmean_part[stile*4096 + b*512 + d0 + dcol] = tot * (1.0f/2048.0f);
    }
}

// ---------------------------------------------------------------------------
// GEMM 1: Sp[b,q,k] = bf16( exp( w[k] * (Qb . Kb^T) / sqrt(512) ) )
// Round-3 proven structure (57.6 us): 128x128 tile, BK=64, 4 waves (2x2),
// XOR-swizzled LDS, 2-phase explicit double-buffer, one __syncthreads per
// K-step. dragon_w applied as f32 per-column scale in the epilogue; epilogue
// writes per-k-block softmax-denominator partials lpart. XCD bijective
// swizzle: 256 consecutive lids = one batch per XCD.
// ---------------------------------------------------------------------------
#define SCALE_QK 0.04419417382415922f

__global__ __launch_bounds__(256) void k_gemm_qk(
    const unsigned short* __restrict__ Qb, const unsigned short* __restrict__ Kb,
    const float* __restrict__ dragon_w,
    unsigned short* __restrict__ Sp, float* __restrict__ lpart)
{
    __shared__ unsigned short A0[128*64], B0[128*64];
    __shared__ unsigned short A1[128*64], B1[128*64];
    int tid = threadIdx.x;
    int lane = tid & 63, wave = tid >> 6;
    int wm = wave >> 1, wn = wave & 1;
    int ln = lane & 15, q4 = lane >> 4;
    int sx = ln & 7;
    int lid = (blockIdx.x & 7)*256 + (blockIdx.x >> 3);
    int kb = lid & 15, qb = (lid >> 4) & 15, b = lid >> 8;
    int q0 = qb*128, k0 = kb*128;
    const unsigned short* Abase = Qb + ((long long)b*2048 + q0)*512;
    const unsigned short* Bbase = Kb + ((long long)b*2048 + k0)*512;

    f32x4 acc[4][4];
    #pragma unroll
    for (int i = 0; i < 4; ++i)
        #pragma unroll
        for (int j = 0; j < 4; ++j) acc[i][j] = (f32x4)0.0f;

    int cc = lane & 7;
    int rg = lane >> 3;

    auto STAGE = [&](unsigned short* dA, unsigned short* dB, int kt){
        #pragma unroll
        for (int c = 0; c < 4; ++c){
            int chunk = wave*4 + c;
            int row = chunk*8 + rg;
            int gc  = cc ^ (row & 7);
            gload_lds16(Abase + (long long)row*512 + kt*64 + gc*8, dA + chunk*512);
            gload_lds16(Bbase + (long long)row*512 + kt*64 + gc*8, dB + chunk*512);
        }
    };
    auto COMPUTE = [&](const unsigned short* At, const unsigned short* Bt){
        #pragma unroll
        for (int ks = 0; ks < 2; ++ks){
            s16x8 af[4], bfr[4];
            int cs = ((ks*4 + q4) ^ sx) * 8;
            #pragma unroll
            for (int i = 0; i < 4; ++i)
                af[i] = *(const s16x8*)&At[(wm*64 + i*16 + ln)*64 + cs];
            #pragma unroll
            for (int j = 0; j < 4; ++j)
                bfr[j] = *(const s16x8*)&Bt[(wn*64 + j*16 + ln)*64 + cs];
            #pragma unroll
            for (int i = 0; i < 4; ++i)
                #pragma unroll
                for (int j = 0; j < 4; ++j)
                    acc[i][j] = __builtin_amdgcn_mfma_f32_16x16x32_bf16(af[i], bfr[j], acc[i][j], 0, 0, 0);
        }
    };

    STAGE(A0, B0, 0); __syncthreads();
    STAGE(A1, B1, 1); COMPUTE(A0, B0); __syncthreads();
    STAGE(A0, B0, 2); COMPUTE(A1, B1); __syncthreads();
    STAGE(A1, B1, 3); COMPUTE(A0, B0); __syncthreads();
    STAGE(A0, B0, 4); COMPUTE(A1, B1); __syncthreads();
    STAGE(A1, B1, 5); COMPUTE(A0, B0); __syncthreads();
    STAGE(A0, B0, 6); COMPUTE(A1, B1); __syncthreads();
    STAGE(A1, B1, 7); COMPUTE(A0, B0); __syncthreads();
    COMPUTE(A1, B1); __syncthreads();

    // epilogue: per-column dragon weight (f32), exp, bf16 store, row-sum
    // partials of the ROUNDED values (exactly what PV multiplies against)
    float wj[4];
    #pragma unroll
    for (int j = 0; j < 4; ++j)
        wj[j] = dragon_w[k0 + wn*64 + j*16 + ln] * SCALE_QK;

    float* lred = (float*)A0;              // [128][2], reuses LDS
    unsigned short* outp = Sp + (long long)b*2048*2048;
    #pragma unroll
    for (int i = 0; i < 4; ++i){
        float rs[4] = {0.f, 0.f, 0.f, 0.f};
        #pragma unroll
        for (int j = 0; j < 4; ++j){
            #pragma unroll
            for (int r = 0; r < 4; ++r){
                int q = q0 + wm*64 + i*16 + q4*4 + r;   // C/D: row=(lane>>4)*4+reg
                int k = k0 + wn*64 + j*16 + ln;         //      col=lane&15
                float v = __expf(acc[i][j][r] * wj[j]);
                unsigned short h = f2bf(v);
                outp[(long long)q*2048 + k] = h;
                rs[r] += bf2f(h);
            }
        }
        #pragma unroll
        for (int r = 0; r < 4; ++r){
            float v = rs[r];
            v += __shfl_xor(v, 1, 16);
            v += __shfl_xor(v, 2, 16);
            v += __shfl_xor(v, 4, 16);
            v += __shfl_xor(v, 8, 16);
            if (ln == 0) lred[(wm*64 + i*16 + q4*4 + r)*2 + wn] = v;
        }
    }
    __syncthreads();
    if (tid < 128)
        lpart[((long long)b*16 + kb)*2048 + q0 + tid] = lred[tid*2] + lred[tid*2+1];
}

// ---------------------------------------------------------------------------
// GEMM 2: out[b,q,d] = blend * (Sp . V) / l[q] + (1-blend) * Vmean[d]
// Round-3 proven structure: 128x128 tile, 4 waves, 2-phase double buffer,
// pure GEMM loop (l from lpart; vmean reduced in the epilogue).
// Grid 512 = exactly 2 blocks/CU at 64 KiB LDS. XCD swizzle: 64 consecutive
// lids = one batch per XCD, db fastest (4 d-siblings share an Sp panel).
// ---------------------------------------------------------------------------
__global__ __launch_bounds__(256) void k_gemm_pv(
    const unsigned short* __restrict__ Sp, const unsigned short* __restrict__ Vt,
    const float* __restrict__ lpart, const float* __restrict__ vmean_part,
    const float* __restrict__ blendp, float* __restrict__ out)
{
    __shared__ unsigned short A0[128*64], B0[128*64];
    __shared__ unsigned short A1[128*64], B1[128*64];
    int tid = threadIdx.x;
    int lane = tid & 63, wave = tid >> 6;
    int wm = wave >> 1, wn = wave & 1;
    int ln = lane & 15, q4 = lane >> 4;
    int sx = ln & 7;
    int lid = (blockIdx.x & 7)*64 + (blockIdx.x >> 3);
    int db = lid & 3, qb = (lid >> 2) & 15, b = lid >> 6;
    int q0 = qb*128, d0 = db*128;
    const unsigned short* Abase = Sp + (long long)b*2048*2048 + (long long)q0*2048;
    const unsigned short* Bbase = Vt + ((long long)b*512 + d0)*2048;

    f32x4 acc[4][4];
    #pragma unroll
    for (int i = 0; i < 4; ++i)
        #pragma unroll
        for (int j = 0; j < 4; ++j) acc[i][j] = (f32x4)0.0f;

    int cc = lane & 7;
    int rg = lane >> 3;

    auto STAGE = [&](unsigned short* dA, unsigned short* dB, int kt){
        #pragma unroll
        for (int c = 0; c < 4; ++c){
            int chunk = wave*4 + c;
            int row = chunk*8 + rg;
            int gc  = cc ^ (row & 7);
            gload_lds16(Abase + (long long)row*2048 + kt*64 + gc*8, dA + chunk*512);
            gload_lds16(Bbase + (long long)row*2048 + kt*64 + gc*8, dB + chunk*512);
        }
    };
    auto COMPUTE = [&](const unsigned short* At, const unsigned short* Bt){
        #pragma unroll
        for (int ks = 0; ks < 2; ++ks){
            s16x8 af[4], bfr[4];
            int cs = ((ks*4 + q4) ^ sx) * 8;
            #pragma unroll
            for (int i = 0; i < 4; ++i)
                af[i] = *(const s16x8*)&At[(wm*64 + i*16 + ln)*64 + cs];
            #pragma unroll
            for (int j = 0; j < 4; ++j)
                bfr[j] = *(const s16x8*)&Bt[(wn*64 + j*16 + ln)*64 + cs];
            #pragma unroll
            for (int i = 0; i < 4; ++i)
                #pragma unroll
                for (int j = 0; j < 4; ++j)
                    acc[i][j] = __builtin_amdgcn_mfma_f32_16x16x32_bf16(af[i], bfr[j], acc[i][j], 0, 0, 0);
        }
    };

    STAGE(A0, B0, 0); __syncthreads();
    for (int kt = 0; kt < 16; ++kt){
        STAGE(A1, B1, 2*kt + 1);
        COMPUTE(A0, B0); __syncthreads();
        if (kt < 15) STAGE(A0, B0, 2*kt + 2);
        COMPUTE(A1, B1); __syncthreads();
    }

    // softmax denominator + vmean, both reduced into LDS
    float* l_sh  = (float*)A0;   // 128 floats
    float* vm_sh = (float*)B0;   // 128 floats
    if (tid < 128){
        float s = 0.f;
        #pragma unroll
        for (int kb = 0; kb < 16; ++kb)
            s += lpart[((long long)b*16 + kb)*2048 + q0 + tid];
        l_sh[tid] = 1.0f / s;
    } else {
        int d = tid - 128;
        float s = 0.f;
        #pragma unroll
        for (int st = 0; st < 32; ++st)
            s += vmean_part[st*4096 + b*512 + d0 + d];
        vm_sh[d] = s;
    }
    __syncthreads();

    float blend = blendp[0];
    float ib = 1.0f - blend;
    float* obase = out + ((long long)b*2048 + q0)*512 + d0;
    float vm[4];
    #pragma unroll
    for (int j = 0; j < 4; ++j) vm[j] = vm_sh[wn*64 + j*16 + ln];
    #pragma unroll
    for (int i = 0; i < 4; ++i){
        #pragma unroll
        for (int r = 0; r < 4; ++r){
            int ql = wm*64 + i*16 + q4*4 + r;
            float linv = l_sh[ql];
            #pragma unroll
            for (int j = 0; j < 4; ++j){
                int dl = wn*64 + j*16 + ln;
                obase[(long long)ql*512 + dl] = blend*acc[i][j][r]*linv + ib*vm[j];
            }
        }
    }
}

// ---------------------------------------------------------------------------
extern "C" void kernel_launch(void* const* d_in, const int* in_sizes, int n_in,
                              void* d_out, int out_size, void* d_ws, size_t ws_size,
                              hipStream_t stream)
{
    (void)in_sizes; (void)n_in; (void)out_size; (void)ws_size;
    const float* Q  = (const float*)d_in[0];
    const float* K  = (const float*)d_in[1];
    const float* V  = (const float*)d_in[2];
    const float* ps = (const float*)d_in[3];
    const float* pb = (const float*)d_in[4];
    const float* w1 = (const float*)d_in[5];
    const float* b1 = (const float*)d_in[6];
    const float* w2 = (const float*)d_in[7];
    const float* b2 = (const float*)d_in[8];
    float* out = (float*)d_out;

    char* ws = (char*)d_ws;
    float* dragon_w        = (float*)(ws);                                        // 8 KiB
    float* blend           = (float*)(ws + 8192);
    float* dscratch        = (float*)(ws + 16384);                                // 16 KiB
    float* vmean_part      = (float*)(ws + 32768);                                // 512 KiB
    size_t off = 32768 + (size_t)512*1024;
    unsigned short* Qb     = (unsigned short*)(ws + off);                         // 16 MiB
    unsigned short* Kb     = (unsigned short*)(ws + off + (size_t)16*1024*1024);  // 16 MiB
    unsigned short* Vt     = (unsigned short*)(ws + off + (size_t)32*1024*1024);  // 16 MiB
    unsigned short* Sp     = (unsigned short*)(ws + off + (size_t)48*1024*1024);  // 64 MiB
    float* lpart           = (float*)(ws + off + (size_t)112*1024*1024);          // 1 MiB

    hipLaunchKernelGGL(k_stage1,  dim3(6145), dim3(256), 0, stream,
                       Q, K, V, ps, pb, w1, b1, w2, b2, dragon_w, blend,
                       dscratch, Qb, Kb, Vt, vmean_part);
    hipLaunchKernelGGL(k_gemm_qk, dim3(2048), dim3(256), 0, stream,
                       Qb, Kb, dragon_w, Sp, lpart);
    hipLaunchKernelGGL(k_gemm_pv, dim3(512),  dim3(256), 0, stream,
                       Sp, Vt, lpart, vmean_part, blend, out);
}

// Round 9
// 236.922 us; speedup vs baseline: 1.2153x; 1.2153x over previous
//
#include <hip/hip_runtime.h>
#include <cstdint>

#define DEV __device__ __forceinline__

typedef float f32x4 __attribute__((ext_vector_type(4)));
typedef short s16x8 __attribute__((ext_vector_type(8)));

DEV unsigned short f2bf(float f){
    unsigned u = __builtin_bit_cast(unsigned, f);
    u = u + 0x7fffu + ((u >> 16) & 1u);   // RNE
    return (unsigned short)(u >> 16);
}
DEV float bf2f(unsigned short h){
    unsigned u = ((unsigned)h) << 16;
    return __builtin_bit_cast(float, u);
}

typedef const void __attribute__((address_space(1)))* gcp;
typedef void __attribute__((address_space(3)))* lp;
DEV void gload_lds16(const void* g, void* l){
    // async global->LDS, 16B per lane; LDS dest = wave-uniform base + lane*16
    __builtin_amdgcn_global_load_lds((gcp)g, (lp)l, 16, 0, 0);
}

// ---------------------------------------------------------------------------
// k-axis permutation applied to Sp and Vt's s-axis (both sides of the PV
// contraction, so PV is unaffected): within each 64-block,
//   pi(k) = ((k&15)<<2) | ((k>>4)&3),  pi^{-1}(a) = ((a&3)<<4) | (a>>2).
// Purpose: qk's epilogue fragment (lane holds k-stride-16 values j=0..3)
// becomes ONE 8-B coalesced store instead of four 2-B scattered stores.
// dragon_w stays indexed by ORIGINAL k; row sums are permutation-invariant.
// ---------------------------------------------------------------------------

// ---------------------------------------------------------------------------
// Stage 1 (grid 6145):
//   block 0          : dragon pattern + blend scalar (256-thread, barriers;
//                      hidden behind the conversion blocks running concurrently)
//   blocks 1..2048   : Q -> bf16
//   blocks 2049..4096: K -> bf16 (UNSCALED; dragon_w applied in qk epilogue)
//   blocks 4097..    : V -> Vt (bf16 [b][d][pi(s)]) + race-free vmean partials
// ---------------------------------------------------------------------------
__global__ __launch_bounds__(256) void k_stage1(
    const float* __restrict__ Q, const float* __restrict__ K,
    const float* __restrict__ V,
    const float* __restrict__ scale, const float* __restrict__ bias,
    const float* __restrict__ w1, const float* __restrict__ b1,
    const float* __restrict__ w2, const float* __restrict__ b2,
    float* __restrict__ dragon_w, float* __restrict__ blend_out,
    unsigned short* __restrict__ Qb, unsigned short* __restrict__ Kb,
    unsigned short* __restrict__ Vt, float* __restrict__ vmean_part)
{
    __shared__ float sh[8704];
    int tid = threadIdx.x;
    int bx  = blockIdx.x;

    if (bx == 0){
        float* A    = sh;          // 4096
        float* Bb   = sh + 4096;   // 4096
        float* sred = sh + 8192;   // 512
        if (tid == 0) A[0] = 0.5f;
        __syncthreads();
        int len = 1;
        for (int it = 1; it < 12; ++it){
            int n = len, nl = 2*n + 1;
            for (int i = tid; i < nl; i += 256){
                float v;
                if (i < n)       v = A[i];
                else if (i == n) v = 0.5f;
                else             v = 1.0f - A[2*n - i];
                Bb[i] = v;
            }
            __syncthreads();
            const float third = 1.0f/3.0f;
            for (int i = tid; i < nl; i += 256){
                float s = Bb[i]*third;
                if (i > 0)    s += Bb[i-1]*third;
                if (i < nl-1) s += Bb[i+1]*third;
                A[i] = s;
            }
            __syncthreads();
            float mn = 3.4e38f, mx = -3.4e38f;
            for (int i = tid; i < nl; i += 256){ float v = A[i]; mn = fminf(mn,v); mx = fmaxf(mx,v); }
            sred[tid] = mn; sred[256 + tid] = mx;
            __syncthreads();
            for (int off = 128; off > 0; off >>= 1){
                if (tid < off){
                    sred[tid]       = fminf(sred[tid],       sred[tid+off]);
                    sred[256 + tid] = fmaxf(sred[256 + tid], sred[256 + tid + off]);
                }
                __syncthreads();
            }
            float lo = sred[0], den = sred[256] - lo + 1e-8f;
            for (int i = tid; i < nl; i += 256) A[i] = (A[i] - lo) / den;
            len = nl;
            __syncthreads();
        }
        float sc = scale[11], bi = bias[11];
        for (int i = tid; i < 2048; i += 256){
            float x = A[2*i]*sc + bi;
            dragon_w[i] = fmaxf(x, 0.f) + log1pf(__expf(-fabsf(x)));  // softplus
        }
        if (tid < 64){
            float h = fmaxf(w1[11*64 + tid] + b1[tid], 0.f);
            float c = h * w2[tid];
            for (int off = 32; off > 0; off >>= 1) c += __shfl_xor(c, off, 64);
            if (tid == 0) blend_out[0] = 1.f/(1.f + __expf(-(c + b2[0])));
        }
        return;
    }

    if (bx <= 4096){
        // ---- Q (1..2048) / K (2049..4096) -> bf16, no scaling ----
        const float* src = (bx <= 2048) ? Q : K;
        unsigned short* dst = (bx <= 2048) ? Qb : Kb;
        int bi = (bx <= 2048) ? (bx-1) : (bx-2049);
        const long long total4 = (long long)8*2048*512/4;   // 2097152
        long long stride = 2048LL*256;
        for (long long i = (long long)bi*256 + tid; i < total4; i += stride){
            long long base = i*4;
            const float4 q = *(const float4*)(src + base);
            ushort4 qo;
            qo.x = f2bf(q.x); qo.y = f2bf(q.y); qo.z = f2bf(q.z); qo.w = f2bf(q.w);
            *(ushort4*)(dst + base) = qo;
        }
        return;
    }

    // ---- V transpose + vmean partials ----
    int t = bx - 4097;                    // 0..2047 = 32 stile x 8 dtile x 8 b
    int stile = t & 31, dtile = (t >> 5) & 7, b = t >> 8;
    int s0 = stile*64, d0 = dtile*64;
    float (*tile)[67] = (float(*)[67])sh;  // 64x67 floats = 4288
    float* red = sh + 4288;                // 256 floats
    int c4 = tid & 15, rr = tid >> 4;
    const float* src = V + ((long long)b*2048 + s0)*512 + d0;
    #pragma unroll
    for (int p = 0; p < 4; ++p){
        int row = p*16 + rr;
        const float4 v = *(const float4*)(src + (long long)row*512 + c4*4);
        tile[row][c4*4+0] = v.x; tile[row][c4*4+1] = v.y;
        tile[row][c4*4+2] = v.z; tile[row][c4*4+3] = v.w;
    }
    __syncthreads();
    // Vt write with pi-permuted s-axis: pi-addr a = c4*4+m holds orig
    // s = pi^{-1}(a) = m*16 + c4  (gather is equally scattered either way)
    unsigned short* dst = Vt + ((long long)b*512 + d0)*2048 + s0;
    #pragma unroll
    for (int p = 0; p < 4; ++p){
        int d = p*16 + rr;
        ushort4 o;
        o.x = f2bf(tile[ 0 + c4][d]);
        o.y = f2bf(tile[16 + c4][d]);
        o.z = f2bf(tile[32 + c4][d]);
        o.w = f2bf(tile[48 + c4][d]);
        *(ushort4*)(dst + (long long)d*2048 + c4*4) = o;
    }
    int dcol = tid & 63, sp = tid >> 6;
    float s = 0.f;
    #pragma unroll
    for (int ii = 0; ii < 16; ++ii) s += tile[sp*16 + ii][dcol];
    red[sp*64 + dcol] = s;
    __syncthreads();
    if (sp == 0){
        float tot = red[dcol] + red[64+dcol] + red[128+dcol] + red[192+dcol];
        vmean_part[stile*4096 + b*512 + d0 + dcol] = tot * (1.0f/2048.0f);
    }
}

// ---------------------------------------------------------------------------
// GEMM 1: Sp[b,q,pi(k)] = bf16( exp( w[k] * (Qb . Kb^T) / sqrt(512) ) )
// Round-3 proven structure (57.6 us): 128x128 tile, BK=64, 4 waves (2x2),
// XOR-swizzled LDS, 2-phase explicit double-buffer, one __syncthreads per
// K-step. dragon_w applied as f32 per-column scale in the epilogue.
// NEW: pi-permuted Sp store — lane's 4 k-stride-16 values (j=0..3) are
// pi-consecutive, so the store is one 8-B ushort4 (4x fewer store uops,
// 128-B segments per 16-lane group instead of 32-B).
// Epilogue writes per-k-block softmax-denominator partials lpart.
// XCD bijective swizzle: 256 consecutive lids = one batch per XCD.
// ---------------------------------------------------------------------------
#define SCALE_QK 0.04419417382415922f

__global__ __launch_bounds__(256) void k_gemm_qk(
    const unsigned short* __restrict__ Qb, const unsigned short* __restrict__ Kb,
    const float* __restrict__ dragon_w,
    unsigned short* __restrict__ Sp, float* __restrict__ lpart)
{
    __shared__ unsigned short A0[128*64], B0[128*64];
    __shared__ unsigned short A1[128*64], B1[128*64];
    int tid = threadIdx.x;
    int lane = tid & 63, wave = tid >> 6;
    int wm = wave >> 1, wn = wave & 1;
    int ln = lane & 15, q4 = lane >> 4;
    int sx = ln & 7;
    int lid = (blockIdx.x & 7)*256 + (blockIdx.x >> 3);
    int kb = lid & 15, qb = (lid >> 4) & 15, b = lid >> 8;
    int q0 = qb*128, k0 = kb*128;
    const unsigned short* Abase = Qb + ((long long)b*2048 + q0)*512;
    const unsigned short* Bbase = Kb + ((long long)b*2048 + k0)*512;

    f32x4 acc[4][4];
    #pragma unroll
    for (int i = 0; i < 4; ++i)
        #pragma unroll
        for (int j = 0; j < 4; ++j) acc[i][j] = (f32x4)0.0f;

    int cc = lane & 7;
    int rg = lane >> 3;

    auto STAGE = [&](unsigned short* dA, unsigned short* dB, int kt){
        #pragma unroll
        for (int c = 0; c < 4; ++c){
            int chunk = wave*4 + c;
            int row = chunk*8 + rg;
            int gc  = cc ^ (row & 7);
            gload_lds16(Abase + (long long)row*512 + kt*64 + gc*8, dA + chunk*512);
            gload_lds16(Bbase + (long long)row*512 + kt*64 + gc*8, dB + chunk*512);
        }
    };
    auto COMPUTE = [&](const unsigned short* At, const unsigned short* Bt){
        #pragma unroll
        for (int ks = 0; ks < 2; ++ks){
            s16x8 af[4], bfr[4];
            int cs = ((ks*4 + q4) ^ sx) * 8;
            #pragma unroll
            for (int i = 0; i < 4; ++i)
                af[i] = *(const s16x8*)&At[(wm*64 + i*16 + ln)*64 + cs];
            #pragma unroll
            for (int j = 0; j < 4; ++j)
                bfr[j] = *(const s16x8*)&Bt[(wn*64 + j*16 + ln)*64 + cs];
            #pragma unroll
            for (int i = 0; i < 4; ++i)
                #pragma unroll
                for (int j = 0; j < 4; ++j)
                    acc[i][j] = __builtin_amdgcn_mfma_f32_16x16x32_bf16(af[i], bfr[j], acc[i][j], 0, 0, 0);
        }
    };

    STAGE(A0, B0, 0); __syncthreads();
    STAGE(A1, B1, 1); COMPUTE(A0, B0); __syncthreads();
    STAGE(A0, B0, 2); COMPUTE(A1, B1); __syncthreads();
    STAGE(A1, B1, 3); COMPUTE(A0, B0); __syncthreads();
    STAGE(A0, B0, 4); COMPUTE(A1, B1); __syncthreads();
    STAGE(A1, B1, 5); COMPUTE(A0, B0); __syncthreads();
    STAGE(A0, B0, 6); COMPUTE(A1, B1); __syncthreads();
    STAGE(A1, B1, 7); COMPUTE(A0, B0); __syncthreads();
    COMPUTE(A1, B1); __syncthreads();

    // epilogue: per-column dragon weight (f32, ORIGINAL k indexing), exp,
    // pi-packed 8-B bf16 store, row-sum partials of the ROUNDED values
    // (exactly what PV multiplies against; same add order as before)
    float wj[4];
    #pragma unroll
    for (int j = 0; j < 4; ++j)
        wj[j] = dragon_w[k0 + wn*64 + j*16 + ln] * SCALE_QK;

    float* lred = (float*)A0;              // [128][2], reuses LDS
    unsigned short* outp = Sp + (long long)b*2048*2048;
    #pragma unroll
    for (int i = 0; i < 4; ++i){
        float rs[4];
        #pragma unroll
        for (int r = 0; r < 4; ++r){
            int q = q0 + wm*64 + i*16 + q4*4 + r;   // C/D: row=(lane>>4)*4+reg
            ushort4 o;
            o.x = f2bf(__expf(acc[i][0][r] * wj[0]));
            o.y = f2bf(__expf(acc[i][1][r] * wj[1]));
            o.z = f2bf(__expf(acc[i][2][r] * wj[2]));
            o.w = f2bf(__expf(acc[i][3][r] * wj[3]));
            // pi-address: orig k = wn*64 + j*16 + ln  ->  pi = wn*64 + ln*4 + j
            *(ushort4*)(outp + (long long)q*2048 + k0 + wn*64 + ln*4) = o;
            rs[r] = bf2f(o.x) + bf2f(o.y) + bf2f(o.z) + bf2f(o.w);
        }
        #pragma unroll
        for (int r = 0; r < 4; ++r){
            float v = rs[r];
            v += __shfl_xor(v, 1, 16);
            v += __shfl_xor(v, 2, 16);
            v += __shfl_xor(v, 4, 16);
            v += __shfl_xor(v, 8, 16);
            if (ln == 0) lred[(wm*64 + i*16 + q4*4 + r)*2 + wn] = v;
        }
    }
    __syncthreads();
    if (tid < 128)
        lpart[((long long)b*16 + kb)*2048 + q0 + tid] = lred[tid*2] + lred[tid*2+1];
}

// ---------------------------------------------------------------------------
// GEMM 2: out[b,q,d] = blend * (Sp . V) / l[q] + (1-blend) * Vmean[d]
// Round-3 proven structure, UNCHANGED: the pi permutation is applied to both
// Sp's k-axis and Vt's s-axis, so the contraction is invariant and this
// kernel's addressing is identical. 128x128 tile, 4 waves, 2-phase dbuf,
// pure GEMM loop; l from lpart; vmean reduced in the epilogue. Grid 512 =
// 2 blocks/CU. XCD swizzle: 64 consecutive lids = one batch per XCD.
// ---------------------------------------------------------------------------
__global__ __launch_bounds__(256) void k_gemm_pv(
    const unsigned short* __restrict__ Sp, const unsigned short* __restrict__ Vt,
    const float* __restrict__ lpart, const float* __restrict__ vmean_part,
    const float* __restrict__ blendp, float* __restrict__ out)
{
    __shared__ unsigned short A0[128*64], B0[128*64];
    __shared__ unsigned short A1[128*64], B1[128*64];
    int tid = threadIdx.x;
    int lane = tid & 63, wave = tid >> 6;
    int wm = wave >> 1, wn = wave & 1;
    int ln = lane & 15, q4 = lane >> 4;
    int sx = ln & 7;
    int lid = (blockIdx.x & 7)*64 + (blockIdx.x >> 3);
    int db = lid & 3, qb = (lid >> 2) & 15, b = lid >> 6;
    int q0 = qb*128, d0 = db*128;
    const unsigned short* Abase = Sp + (long long)b*2048*2048 + (long long)q0*2048;
    const unsigned short* Bbase = Vt + ((long long)b*512 + d0)*2048;

    f32x4 acc[4][4];
    #pragma unroll
    for (int i = 0; i < 4; ++i)
        #pragma unroll
        for (int j = 0; j < 4; ++j) acc[i][j] = (f32x4)0.0f;

    int cc = lane & 7;
    int rg = lane >> 3;

    auto STAGE = [&](unsigned short* dA, unsigned short* dB, int kt){
        #pragma unroll
        for (int c = 0; c < 4; ++c){
            int chunk = wave*4 + c;
            int row = chunk*8 + rg;
            int gc  = cc ^ (row & 7);
            gload_lds16(Abase + (long long)row*2048 + kt*64 + gc*8, dA + chunk*512);
            gload_lds16(Bbase + (long long)row*2048 + kt*64 + gc*8, dB + chunk*512);
        }
    };
    auto COMPUTE = [&](const unsigned short* At, const unsigned short* Bt){
        #pragma unroll
        for (int ks = 0; ks < 2; ++ks){
            s16x8 af[4], bfr[4];
            int cs = ((ks*4 + q4) ^ sx) * 8;
            #pragma unroll
            for (int i = 0; i < 4; ++i)
                af[i] = *(const s16x8*)&At[(wm*64 + i*16 + ln)*64 + cs];
            #pragma unroll
            for (int j = 0; j < 4; ++j)
                bfr[j] = *(const s16x8*)&Bt[(wn*64 + j*16 + ln)*64 + cs];
            #pragma unroll
            for (int i = 0; i < 4; ++i)
                #pragma unroll
                for (int j = 0; j < 4; ++j)
                    acc[i][j] = __builtin_amdgcn_mfma_f32_16x16x32_bf16(af[i], bfr[j], acc[i][j], 0, 0, 0);
        }
    };

    STAGE(A0, B0, 0); __syncthreads();
    for (int kt = 0; kt < 16; ++kt){
        STAGE(A1, B1, 2*kt + 1);
        COMPUTE(A0, B0); __syncthreads();
        if (kt < 15) STAGE(A0, B0, 2*kt + 2);
        COMPUTE(A1, B1); __syncthreads();
    }

    // softmax denominator + vmean, both reduced into LDS
    float* l_sh  = (float*)A0;   // 128 floats
    float* vm_sh = (float*)B0;   // 128 floats
    if (tid < 128){
        float s = 0.f;
        #pragma unroll
        for (int kb = 0; kb < 16; ++kb)
            s += lpart[((long long)b*16 + kb)*2048 + q0 + tid];
        l_sh[tid] = 1.0f / s;
    } else {
        int d = tid - 128;
        float s = 0.f;
        #pragma unroll
        for (int st = 0; st < 32; ++st)
            s += vmean_part[st*4096 + b*512 + d0 + d];
        vm_sh[d] = s;
    }
    __syncthreads();

    float blend = blendp[0];
    float ib = 1.0f - blend;
    float* obase = out + ((long long)b*2048 + q0)*512 + d0;
    float vm[4];
    #pragma unroll
    for (int j = 0; j < 4; ++j) vm[j] = vm_sh[wn*64 + j*16 + ln];
    #pragma unroll
    for (int i = 0; i < 4; ++i){
        #pragma unroll
        for (int r = 0; r < 4; ++r){
            int ql = wm*64 + i*16 + q4*4 + r;
            float linv = l_sh[ql];
            #pragma unroll
            for (int j = 0; j < 4; ++j){
                int dl = wn*64 + j*16 + ln;
                obase[(long long)ql*512 + dl] = blend*acc[i][j][r]*linv + ib*vm[j];
            }
        }
    }
}

// ---------------------------------------------------------------------------
extern "C" void kernel_launch(void* const* d_in, const int* in_sizes, int n_in,
                              void* d_out, int out_size, void* d_ws, size_t ws_size,
                              hipStream_t stream)
{
    (void)in_sizes; (void)n_in; (void)out_size; (void)ws_size;
    const float* Q  = (const float*)d_in[0];
    const float* K  = (const float*)d_in[1];
    const float* V  = (const float*)d_in[2];
    const float* ps = (const float*)d_in[3];
    const float* pb = (const float*)d_in[4];
    const float* w1 = (const float*)d_in[5];
    const float* b1 = (const float*)d_in[6];
    const float* w2 = (const float*)d_in[7];
    const float* b2 = (const float*)d_in[8];
    float* out = (float*)d_out;

    char* ws = (char*)d_ws;
    float* dragon_w        = (float*)(ws);                                        // 8 KiB
    float* blend           = (float*)(ws + 8192);
    float* vmean_part      = (float*)(ws + 32768);                                // 512 KiB
    size_t off = 32768 + (size_t)512*1024;
    unsigned short* Qb     = (unsigned short*)(ws + off);                         // 16 MiB
    unsigned short* Kb     = (unsigned short*)(ws + off + (size_t)16*1024*1024);  // 16 MiB
    unsigned short* Vt     = (unsigned short*)(ws + off + (size_t)32*1024*1024);  // 16 MiB
    unsigned short* Sp     = (unsigned short*)(ws + off + (size_t)48*1024*1024);  // 64 MiB
    float* lpart           = (float*)(ws + off + (size_t)112*1024*1024);          // 1 MiB

    hipLaunchKernelGGL(k_stage1,  dim3(6145), dim3(256), 0, stream,
                       Q, K, V, ps, pb, w1, b1, w2, b2, dragon_w, blend,
                       Qb, Kb, Vt, vmean_part);
    hipLaunchKernelGGL(k_gemm_qk, dim3(2048), dim3(256), 0, stream,
                       Qb, Kb, dragon_w, Sp, lpart);
    hipLaunchKernelGGL(k_gemm_pv, dim3(512),  dim3(256), 0, stream,
                       Sp, Vt, lpart, vmean_part, blend, out);
}